// Round 4
// baseline (1319.470 us; speedup 1.0000x reference)
//
#include <hip/hip_runtime.h>
#include <hip/hip_bf16.h>

typedef short bf16x8 __attribute__((ext_vector_type(8)));
typedef float f32x4  __attribute__((ext_vector_type(4)));

#define TSTEPS 1000
#define BATCH  256
#define NIN    256
#define HID    128
#define TC     40
#define LOG2E  1.44269504088896f

// xp SoA keyed to the 16-wave consumer:
//   gidx2 = ((btile*8 + g)*2 + kh)*64 + lane   in [0, 16384)
//   xpA[ (dir*T + t)*16384 + gidx2 ] : uint2 = {pk2(xr0,xr1), pk2(xz0,xz1)}
//   xpB[ ... same index ...        ] : uint  =  pk2(xn0,xn1)
// (elements 0,1 for kh=0; 2,3 for kh=1; all prescaled by log2e, biases folded)
#define GIDX2_N 16384
#define XPA_ELEMS (2ull*TSTEPS*GIDX2_N)
#define XPB_OFF_BYTES (XPA_ELEMS*8ull)                 // 262,144,000
#define XP_NEED (XPA_ELEMS*8ull + XPA_ELEMS*4ull)      // 393,216,000

__device__ __forceinline__ ushort f2bf(float f){
  union { float f; unsigned u; } v; v.f = f;
  unsigned r = v.u + 0x7fffu + ((v.u >> 16) & 1u);
  return (ushort)(r >> 16);
}
__device__ __forceinline__ uint pk2(float lo, float hi){
  __hip_bfloat162 h = __float22bfloat162_rn(make_float2(lo, hi));
  union { __hip_bfloat162 h; uint u; } c; c.h = h; return c.u;
}
__device__ __forceinline__ float bflo(uint w){ union{uint u;float f;}c; c.u = w<<16; return c.f; }
__device__ __forceinline__ float bfhi(uint w){ union{uint u;float f;}c; c.u = w & 0xffff0000u; return c.f; }

__device__ __forceinline__ float sigmoid_fast(float x){
  return __builtin_amdgcn_rcpf(1.f + __expf(-x));
}
__device__ __forceinline__ float tanh_fast(float a){
  const float e = __expf(2.f*fabsf(a));
  const float t = fmaf(-2.f, __builtin_amdgcn_rcpf(e + 1.f), 1.f);
  return copysignf(t, a);
}
__device__ __forceinline__ bf16x8 ld_w8(const float* p){
  union { uint u[4]; bf16x8 v; } c;
  c.u[0]=pk2(p[0],p[1]); c.u[1]=pk2(p[2],p[3]);
  c.u[2]=pk2(p[4],p[5]); c.u[3]=pk2(p[6],p[7]);
  return c.v;
}
__device__ __forceinline__ bf16x8 ld_w8s(const float* p, float s){
  union { uint u[4]; bf16x8 v; } c;
  c.u[0]=pk2(p[0]*s,p[1]*s); c.u[1]=pk2(p[2]*s,p[3]*s);
  c.u[2]=pk2(p[4]*s,p[5]*s); c.u[3]=pk2(p[6]*s,p[7]*s);
  return c.v;
}

// ============================================================================
// Input-projection GEMM -> pair-ownership SoA layout, prescaled by log2e.
// ============================================================================
__global__ __launch_bounds__(512) void xp_gemm(
    const float* __restrict__ y_aux,
    const float* __restrict__ Wf, const float* __restrict__ bihf, const float* __restrict__ bhhf,
    const float* __restrict__ Wb, const float* __restrict__ bihb, const float* __restrict__ bhhb,
    uint2* __restrict__ xpA, uint* __restrict__ xpB)
{
  const int nch = TSTEPS/TC;
  const int blk = blockIdx.x;
  const int dir = blk / (16*nch);
  const int rem = blk % (16*nch);
  const int btile = rem / nch;
  const int tch = rem % nch;
  const int b0 = btile*16;
  const int tid=threadIdx.x, wave=tid>>6, lane=tid&63, lrow=lane&15, lgrp=lane>>4;
  const float* Wih = dir? Wb : Wf;
  const float* bih = dir? bihb : bihf;
  const float* bhh = dir? bhhb : bhhf;

  __shared__ __align__(16) ushort xsh[2][16][264];

  bf16x8 wf[3][8];
  float biass[3];
  #pragma unroll
  for (int t3=0;t3<3;++t3){
    const int g = t3*128 + wave*16 + lrow;
    #pragma unroll
    for (int kk=0;kk<8;++kk)
      wf[t3][kk] = ld_w8(Wih + g*NIN + kk*32 + lgrp*8);
    biass[t3] = LOG2E * (bih[g] + (t3<2 ? bhh[g] : 0.f));
  }

  const int row = tid>>5, f8 = tid&31;
  const float* xsrc = y_aux + (size_t)(b0+row)*(TSTEPS*NIN) + (size_t)(tch*TC)*NIN + f8*8;
  {
    float4 a = *(const float4*)xsrc;
    float4 b = *(const float4*)(xsrc+4);
    union{uint u[4]; bf16x8 v;} c;
    c.u[0]=pk2(a.x,a.y); c.u[1]=pk2(a.z,a.w); c.u[2]=pk2(b.x,b.y); c.u[3]=pk2(b.z,b.w);
    *(bf16x8*)&xsh[0][row][f8*8] = c.v;
  }
  __syncthreads();

  size_t sidx = ((size_t)dir*TSTEPS + (size_t)(tch*TC))*GIDX2_N
              + (size_t)(((btile*8 + wave)*2)*64 + lane);

  for (int k=0;k<TC;++k){
    const int cur=k&1, nxt=cur^1;
    const bool more = (k < TC-1);
    float4 pa, pb;
    if (more){
      const float* p = xsrc + (size_t)(k+1)*NIN;
      pa = *(const float4*)p;
      pb = *(const float4*)(p+4);
    }
    f32x4 a0={0,0,0,0}, a1={0,0,0,0}, a2={0,0,0,0};
    #pragma unroll
    for (int kk=0;kk<8;++kk){
      bf16x8 a = *(const bf16x8*)&xsh[cur][lrow][kk*32 + lgrp*8];
      a0 = __builtin_amdgcn_mfma_f32_16x16x32_bf16(a, wf[0][kk], a0, 0,0,0);
      a1 = __builtin_amdgcn_mfma_f32_16x16x32_bf16(a, wf[1][kk], a1, 0,0,0);
      a2 = __builtin_amdgcn_mfma_f32_16x16x32_bf16(a, wf[2][kk], a2, 0,0,0);
    }
    const float r0=fmaf(LOG2E,a0[0],biass[0]), r1=fmaf(LOG2E,a0[1],biass[0]);
    const float r2=fmaf(LOG2E,a0[2],biass[0]), r3=fmaf(LOG2E,a0[3],biass[0]);
    const float z0=fmaf(LOG2E,a1[0],biass[1]), z1=fmaf(LOG2E,a1[1],biass[1]);
    const float z2=fmaf(LOG2E,a1[2],biass[1]), z3=fmaf(LOG2E,a1[3],biass[1]);
    const float n0=fmaf(LOG2E,a2[0],biass[2]), n1=fmaf(LOG2E,a2[1],biass[2]);
    const float n2=fmaf(LOG2E,a2[2],biass[2]), n3=fmaf(LOG2E,a2[3],biass[2]);
    uint2 qa0; qa0.x = pk2(r0,r1); qa0.y = pk2(z0,z1);
    uint2 qa1; qa1.x = pk2(r2,r3); qa1.y = pk2(z2,z3);
    xpA[sidx]    = qa0;
    xpA[sidx+64] = qa1;
    xpB[sidx]    = pk2(n0,n1);
    xpB[sidx+64] = pk2(n2,n3);
    sidx += GIDX2_N;
    if (more){
      union{uint u[4]; bf16x8 v;} c;
      c.u[0]=pk2(pa.x,pa.y); c.u[1]=pk2(pa.z,pa.w); c.u[2]=pk2(pb.x,pb.y); c.u[3]=pk2(pb.z,pb.w);
      *(bf16x8*)&xsh[nxt][row][f8*8] = c.v;
    }
    asm volatile("s_waitcnt lgkmcnt(0)\n\ts_barrier" ::: "memory");
  }
}

// ============================================================================
// Serial recurrence, 16 waves/block, K-split pairs.
// Wave (g = wave>>1, kh = wave&1): 3 gates x cols [16g,16g+16) x K in
// [64kh, 64kh+64). Pair sums partials via LDS; wave owns elements
// oe = {2kh, 2kh+1} (batch rows lgrp*4+oe) for gates + h publish.
// ============================================================================
__global__ __launch_bounds__(1024) void gru_rec16(
    const uint2* __restrict__ xpA, const uint* __restrict__ xpB,
    const float* __restrict__ Whhf, const float* __restrict__ bhhf,
    const float* __restrict__ Whhb, const float* __restrict__ bhhb,
    float* __restrict__ out)
{
  const int blk=blockIdx.x, dir=blk>>4, btile=blk&15, b0=btile<<4;
  const int tid=threadIdx.x, wave=tid>>6, lane=tid&63, lrow=lane&15, lgrp=lane>>4;
  const int g = wave>>1, kh = wave&1;
  const float* Whh = dir? Whhb : Whhf;
  const float* bhh = dir? bhhb : bhhf;

  __shared__ __align__(16) ushort hbuf[2][16][136];
  __shared__ __align__(16) float rA[16][64][4];   // r,z partner partials
  __shared__ __align__(16) float rB[16][64][2];   // n partner partials

  bf16x8 whh[3][2];
  #pragma unroll
  for (int t3=0;t3<3;++t3){
    const int gr = t3*128 + g*16 + lrow;
    #pragma unroll
    for (int kk=0;kk<2;++kk)
      whh[t3][kk] = ld_w8s(Whh + gr*HID + kh*64 + kk*32 + lgrp*8, LOG2E);
  }
  const int hcol = g*16 + lrow;
  const float bh2s = LOG2E * bhh[256 + hcol];
  const int oe = kh*2;               // owned elements oe, oe+1
  const int pe = 2 - oe;             // partner's owned elements

  { ushort* hb=&hbuf[0][0][0]; for (int i=tid;i<16*136;i+=1024) hb[i]=0; }

  const int tt0 = dir? (TSTEPS-1):0;
  const long long dstep = dir? -(long long)GIDX2_N : (long long)GIDX2_N;
  const size_t gb = ((size_t)dir*TSTEPS + (size_t)tt0)*GIDX2_N
                  + (size_t)(((btile*8+g)*2+kh)*64 + lane);
  const uint2* pAp = xpA + gb;
  const uint*  pBp = xpB + gb;
  uint2 qA0 = pAp[0], qA1 = pAp[dstep];
  uint  qB0 = pBp[0], qB1 = pBp[dstep];
  const uint2* fA = pAp + 2*dstep;
  const uint*  fB = pBp + 2*dstep;

  float* op = out + 8192 + (size_t)tt0*(BATCH*2*HID)
            + (size_t)(b0 + lgrp*4 + oe)*(2*HID) + dir*HID + hcol;
  const long long odel = dir? -(long long)(BATCH*2*HID) : (long long)(BATCH*2*HID);

  float hm0=0.f, hm1=0.f;
  __syncthreads();

  for (int s=0;s<TSTEPS;++s){
    const int cur=s&1, nxt=cur^1;
    // depth-2 prefetch (wrap-safe inside the xp allocations)
    uint2 qA2 = *fA; fA += dstep;
    uint  qB2 = *fB; fB += dstep;

    f32x4 ar={0,0,0,0}, az={0,0,0,0}, an={0,0,0,0};
    {
      bf16x8 a0 = *(const bf16x8*)&hbuf[cur][lrow][kh*64 + lgrp*8];
      bf16x8 a1 = *(const bf16x8*)&hbuf[cur][lrow][kh*64 + 32 + lgrp*8];
      ar = __builtin_amdgcn_mfma_f32_16x16x32_bf16(a0, whh[0][0], ar, 0,0,0);
      az = __builtin_amdgcn_mfma_f32_16x16x32_bf16(a0, whh[1][0], az, 0,0,0);
      an = __builtin_amdgcn_mfma_f32_16x16x32_bf16(a0, whh[2][0], an, 0,0,0);
      ar = __builtin_amdgcn_mfma_f32_16x16x32_bf16(a1, whh[0][1], ar, 0,0,0);
      az = __builtin_amdgcn_mfma_f32_16x16x32_bf16(a1, whh[1][1], az, 0,0,0);
      an = __builtin_amdgcn_mfma_f32_16x16x32_bf16(a1, whh[2][1], an, 0,0,0);
    }

    // ship partner's elements
    f32x4 w4; w4[0]=ar[pe]; w4[1]=ar[pe+1]; w4[2]=az[pe]; w4[3]=az[pe+1];
    *(f32x4*)&rA[wave][lane][0] = w4;
    float2 w2; w2.x=an[pe]; w2.y=an[pe+1];
    *(float2*)&rB[wave][lane][0] = w2;
    asm volatile("s_waitcnt lgkmcnt(0)\n\ts_barrier" ::: "memory");

    const f32x4 p4 = *(const f32x4*)&rA[wave^1][lane][0];
    const float2 p2 = *(const float2*)&rB[wave^1][lane][0];
    const float R0 = ar[oe]   + p4[0];
    const float R1 = ar[oe+1] + p4[1];
    const float Z0 = az[oe]   + p4[2];
    const float Z1 = az[oe+1] + p4[3];
    const float N0 = an[oe]   + p2.x;
    const float N1 = an[oe+1] + p2.y;

    const float xr0=bflo(qA0.x), xr1=bfhi(qA0.x);
    const float xz0=bflo(qA0.y), xz1=bfhi(qA0.y);
    const float xn0=bflo(qB0),   xn1=bfhi(qB0);

    float hv0, hv1;
    {
      const float r = __builtin_amdgcn_rcpf(1.f + __builtin_amdgcn_exp2f(-(R0+xr0)));
      const float z = __builtin_amdgcn_rcpf(1.f + __builtin_amdgcn_exp2f(-(Z0+xz0)));
      const float y  = fmaf(r, N0+bh2s, xn0);
      const float y2 = y + y;
      const float e  = __builtin_amdgcn_exp2f(fabsf(y2));
      const float t  = fmaf(-2.f, __builtin_amdgcn_rcpf(e+1.f), 1.f);
      const float n  = copysignf(t, y);
      hv0 = fmaf(z, hm0-n, n);  hm0 = hv0;
    }
    {
      const float r = __builtin_amdgcn_rcpf(1.f + __builtin_amdgcn_exp2f(-(R1+xr1)));
      const float z = __builtin_amdgcn_rcpf(1.f + __builtin_amdgcn_exp2f(-(Z1+xz1)));
      const float y  = fmaf(r, N1+bh2s, xn1);
      const float y2 = y + y;
      const float e  = __builtin_amdgcn_exp2f(fabsf(y2));
      const float t  = fmaf(-2.f, __builtin_amdgcn_rcpf(e+1.f), 1.f);
      const float n  = copysignf(t, y);
      hv1 = fmaf(z, hm1-n, n);  hm1 = hv1;
    }

    op[0]   = hv0;
    op[256] = hv1;
    const uint p01 = pk2(hv0, hv1);
    hbuf[nxt][lgrp*4+oe  ][hcol] = (ushort)p01;
    hbuf[nxt][lgrp*4+oe+1][hcol] = (ushort)(p01>>16);

    op += odel;
    qA0=qA1; qA1=qA2; qB0=qB1; qB1=qB2;
    asm volatile("s_waitcnt lgkmcnt(0)\n\ts_barrier" ::: "memory");
  }
}

// ============================================================================
// Fallback fused kernel (used only if ws_size is too small)
// ============================================================================
__global__ __launch_bounds__(512) void gru_fused(
    const float* __restrict__ y_aux,
    const float* __restrict__ W_ih_f, const float* __restrict__ W_hh_f,
    const float* __restrict__ b_ih_f, const float* __restrict__ b_hh_f,
    const float* __restrict__ W_ih_b, const float* __restrict__ W_hh_b,
    const float* __restrict__ b_ih_b, const float* __restrict__ b_hh_b,
    float* __restrict__ out)
{
  const int blk  = blockIdx.x;
  const int dir  = blk >> 4;
  const int b0   = (blk & 15) << 4;
  const int tid  = threadIdx.x;
  const int wave = tid >> 6;
  const int lane = tid & 63;
  const int lrow = lane & 15;
  const int lgrp = lane >> 4;

  const float* Wih = dir ? W_ih_b : W_ih_f;
  const float* Whh = dir ? W_hh_b : W_hh_f;
  const float* bih = dir ? b_ih_b : b_ih_f;
  const float* bhh = dir ? b_hh_b : b_hh_f;

  __shared__ __align__(16) ushort hbuf[2][16][136];
  __shared__ __align__(16) ushort xbuf[2][16][264];

  bf16x8 wih_f[3][8];
  bf16x8 whh_f[3][4];
  #pragma unroll
  for (int t3 = 0; t3 < 3; ++t3){
    const int g = t3*128 + wave*16 + lrow;
    #pragma unroll
    for (int kk = 0; kk < 8; ++kk) wih_f[t3][kk] = ld_w8(Wih + g*NIN + kk*32 + lgrp*8);
    #pragma unroll
    for (int kk = 0; kk < 4; ++kk) whh_f[t3][kk] = ld_w8(Whh + g*HID + kk*32 + lgrp*8);
  }
  float bihv[3], bhhv[3];
  #pragma unroll
  for (int t3 = 0; t3 < 3; ++t3){
    const int g = t3*128 + wave*16 + lrow;
    bihv[t3] = bih[g];
    bhhv[t3] = bhh[g];
  }

  for (int i = tid; i < 2*16*136; i += 512) ((ushort*)hbuf)[i] = 0;
  {
    const int row = tid >> 5, f8 = tid & 31;
    const int t0  = dir ? (TSTEPS-1) : 0;
    const float* p = y_aux + (size_t)(b0+row)*(TSTEPS*NIN) + (size_t)t0*NIN + f8*8;
    union{uint u[4]; bf16x8 v;} c;
    float4 a = *(const float4*)p; float4 b = *(const float4*)(p+4);
    c.u[0]=pk2(a.x,a.y); c.u[1]=pk2(a.z,a.w); c.u[2]=pk2(b.x,b.y); c.u[3]=pk2(b.z,b.w);
    *(bf16x8*)&xbuf[0][row][f8*8] = c.v;
  }
  __syncthreads();

  float hm[4] = {0.f, 0.f, 0.f, 0.f};
  const int hcol = wave*16 + lrow;
  float* outr = out + 8192;

  for (int s = 0; s < TSTEPS; ++s){
    const int tt  = dir ? (TSTEPS-1-s) : s;
    const int cur = s & 1, nxt = cur ^ 1;
    const int tn   = dir ? (tt-1) : (tt+1);
    const int prow = tid >> 5, pf8 = tid & 31;
    const bool more = (s < TSTEPS-1);
    float4 pa, pb;
    if (more){
      const float* p = y_aux + (size_t)(b0+prow)*(TSTEPS*NIN) + (size_t)tn*NIN + pf8*8;
      pa = *(const float4*)p;
      pb = *(const float4*)(p+4);
    }

    f32x4 a_rh = {0,0,0,0}, a_zh = {0,0,0,0}, a_nh = {0,0,0,0};
    f32x4 a_rx = {0,0,0,0}, a_zx = {0,0,0,0}, a_nx = {0,0,0,0};
    #pragma unroll
    for (int kk = 0; kk < 4; ++kk){
      bf16x8 a = *(const bf16x8*)&hbuf[cur][lrow][kk*32 + lgrp*8];
      a_rh = __builtin_amdgcn_mfma_f32_16x16x32_bf16(a, whh_f[0][kk], a_rh, 0,0,0);
      a_zh = __builtin_amdgcn_mfma_f32_16x16x32_bf16(a, whh_f[1][kk], a_zh, 0,0,0);
      a_nh = __builtin_amdgcn_mfma_f32_16x16x32_bf16(a, whh_f[2][kk], a_nh, 0,0,0);
    }
    #pragma unroll
    for (int kk = 0; kk < 8; ++kk){
      bf16x8 a = *(const bf16x8*)&xbuf[cur][lrow][kk*32 + lgrp*8];
      a_rx = __builtin_amdgcn_mfma_f32_16x16x32_bf16(a, wih_f[0][kk], a_rx, 0,0,0);
      a_zx = __builtin_amdgcn_mfma_f32_16x16x32_bf16(a, wih_f[1][kk], a_zx, 0,0,0);
      a_nx = __builtin_amdgcn_mfma_f32_16x16x32_bf16(a, wih_f[2][kk], a_nx, 0,0,0);
    }

    #pragma unroll
    for (int i = 0; i < 4; ++i){
      const float rp  = a_rh[i] + a_rx[i] + bihv[0] + bhhv[0];
      const float zp  = a_zh[i] + a_zx[i] + bihv[1] + bhhv[1];
      const float hnp = a_nh[i] + bhhv[2];
      const float xnp = a_nx[i] + bihv[2];
      const float r = sigmoid_fast(rp);
      const float z = sigmoid_fast(zp);
      const float n = tanh_fast(fmaf(r, hnp, xnp));
      const float hv = n + z*(hm[i] - n);
      hm[i] = hv;
      outr[(size_t)tt*(BATCH*2*HID) + (size_t)(b0 + lgrp*4 + i)*(2*HID)
           + dir*HID + hcol] = hv;
      hbuf[nxt][lgrp*4 + i][hcol] = f2bf(hv);
    }

    if (more){
      union{uint u[4]; bf16x8 v;} c;
      c.u[0]=pk2(pa.x,pa.y); c.u[1]=pk2(pa.z,pa.w); c.u[2]=pk2(pb.x,pb.y); c.u[3]=pk2(pb.z,pb.w);
      *(bf16x8*)&xbuf[nxt][prow][pf8*8] = c.v;
    }
    __syncthreads();
  }
}

// mu_0 / log_var_0 heads: temp = [zeros(B,L), hn0], so only W[:, L:] matters.
__global__ void heads(const float* __restrict__ out_rnn,
    const float* __restrict__ W_mu, const float* __restrict__ b_mu,
    const float* __restrict__ W_lv, const float* __restrict__ b_lv,
    float* __restrict__ out)
{
  const int oid   = blockIdx.x*256 + threadIdx.x;
  const int which = oid >> 12;
  const int r     = oid & 4095;
  const int b = r >> 4, j = r & 15;
  const float* W    = which ? W_lv : W_mu;
  const float* bias = which ? b_lv : b_mu;
  const float* h = out_rnn + b*256;
  const float* w = W + j*272 + 16;
  float acc = bias[j];
  for (int c = 0; c < 256; c += 4){
    acc += h[c]*w[c] + h[c+1]*w[c+1] + h[c+2]*w[c+2] + h[c+3]*w[c+3];
  }
  out[(which << 12) + r] = acc;
}

extern "C" void kernel_launch(void* const* d_in, const int* in_sizes, int n_in,
                              void* d_out, int out_size, void* d_ws, size_t ws_size,
                              hipStream_t stream)
{
  const float* y    = (const float*)d_in[0];
  const float* Wihf = (const float*)d_in[1];
  const float* Whhf = (const float*)d_in[2];
  const float* bihf = (const float*)d_in[3];
  const float* bhhf = (const float*)d_in[4];
  const float* Wihb = (const float*)d_in[5];
  const float* Whhb = (const float*)d_in[6];
  const float* bihb = (const float*)d_in[7];
  const float* bhhb = (const float*)d_in[8];
  const float* Wmu  = (const float*)d_in[9];
  const float* bmu  = (const float*)d_in[10];
  const float* Wlv  = (const float*)d_in[11];
  const float* blv  = (const float*)d_in[12];
  float* out = (float*)d_out;

  if (ws_size >= (size_t)XP_NEED){
    uint2* xpA = (uint2*)d_ws;
    uint*  xpB = (uint*)((char*)d_ws + XPB_OFF_BYTES);
    xp_gemm<<<dim3(2*16*(TSTEPS/TC)), dim3(512), 0, stream>>>(
        y, Wihf, bihf, bhhf, Wihb, bihb, bhhb, xpA, xpB);
    gru_rec16<<<dim3(32), dim3(1024), 0, stream>>>(
        xpA, xpB, Whhf, bhhf, Whhb, bhhb, out);
  } else {
    gru_fused<<<dim3(32), dim3(512), 0, stream>>>(
        y, Wihf, Whhf, bihf, bhhf, Wihb, Whhb, bihb, bhhb, out);
  }
  heads<<<dim3(32), dim3(256), 0, stream>>>(out + 8192, Wmu, bmu, Wlv, blv, out);
}

// Round 5
// 998.693 us; speedup vs baseline: 1.3212x; 1.3212x over previous
//
#include <hip/hip_runtime.h>
#include <hip/hip_bf16.h>

typedef short bf16x8 __attribute__((ext_vector_type(8)));
typedef float f32x4  __attribute__((ext_vector_type(4)));

#define TSTEPS 1000
#define BATCH  256
#define NIN    256
#define HID    128
#define TC     50
#define LOG2E  1.44269504088896f

// SoA xp: xp4 = uint4 region {r01,r23,z01,z23}, xp2 = uint2 region {n01,n23}.
// index = ((dir*TSTEPS + t)*8192 + gidx), gidx = (btile*8+wave)*64+lane.
// r,z prescaled by log2e (biases bih+bhh folded); n prescaled by 2*log2e
// (bih folded; bhh_n stays in gru_rec).
#define GIDX_N 8192
#define XP4_ELEMS (2ull*TSTEPS*GIDX_N)
#define XP2_OFF_BYTES (XP4_ELEMS*16ull)           // 262,144,000
#define XP_NEED (XP4_ELEMS*16ull + 2ull*TSTEPS*GIDX_N*8ull)   // 393,216,000

__device__ __forceinline__ ushort f2bf(float f){
  union { float f; unsigned u; } v; v.f = f;
  unsigned r = v.u + 0x7fffu + ((v.u >> 16) & 1u);
  return (ushort)(r >> 16);
}
__device__ __forceinline__ uint pk2(float lo, float hi){
  __hip_bfloat162 h = __float22bfloat162_rn(make_float2(lo, hi));
  union { __hip_bfloat162 h; uint u; } c; c.h = h; return c.u;
}
__device__ __forceinline__ float bflo(uint w){ union{uint u;float f;}c; c.u = w<<16; return c.f; }
__device__ __forceinline__ float bfhi(uint w){ union{uint u;float f;}c; c.u = w & 0xffff0000u; return c.f; }

__device__ __forceinline__ float sigmoid_fast(float x){
  return __builtin_amdgcn_rcpf(1.f + __expf(-x));
}
__device__ __forceinline__ float tanh_fast(float a){
  const float e = __expf(2.f*fabsf(a));
  const float t = fmaf(-2.f, __builtin_amdgcn_rcpf(e + 1.f), 1.f);
  return copysignf(t, a);
}
__device__ __forceinline__ bf16x8 ld_w8(const float* p){
  union { uint u[4]; bf16x8 v; } c;
  c.u[0]=pk2(p[0],p[1]); c.u[1]=pk2(p[2],p[3]);
  c.u[2]=pk2(p[4],p[5]); c.u[3]=pk2(p[6],p[7]);
  return c.v;
}
__device__ __forceinline__ bf16x8 ld_w8s(const float* p, float s){
  union { uint u[4]; bf16x8 v; } c;
  c.u[0]=pk2(p[0]*s,p[1]*s); c.u[1]=pk2(p[2]*s,p[3]*s);
  c.u[2]=pk2(p[4]*s,p[5]*s); c.u[3]=pk2(p[6]*s,p[7]*s);
  return c.v;
}

// ============================================================================
// Input-projection GEMM. Weights prescaled (r,z: log2e; n: 2*log2e); biases
// folded via MFMA C-operand init. Depth-2 register prefetch of x.
// ============================================================================
__global__ __launch_bounds__(512) void xp_gemm(
    const float* __restrict__ y_aux,
    const float* __restrict__ Wf, const float* __restrict__ bihf, const float* __restrict__ bhhf,
    const float* __restrict__ Wb, const float* __restrict__ bihb, const float* __restrict__ bhhb,
    uint4* __restrict__ xp4, uint2* __restrict__ xp2)
{
  const int nch = TSTEPS/TC;
  const int blk = blockIdx.x;
  const int dir = blk / (16*nch);
  const int rem = blk % (16*nch);
  const int btile = rem / nch;
  const int tch = rem % nch;
  const int b0 = btile*16;
  const int tid=threadIdx.x, wave=tid>>6, lane=tid&63, lrow=lane&15, lgrp=lane>>4;
  const float* Wih = dir? Wb : Wf;
  const float* bih = dir? bihb : bihf;
  const float* bhh = dir? bhhb : bhhf;

  __shared__ __align__(16) ushort xsh[2][16][264];

  const float wscale[3] = {LOG2E, LOG2E, 2.f*LOG2E};
  bf16x8 wf[3][8];
  f32x4 cinit[3];
  #pragma unroll
  for (int t3=0;t3<3;++t3){
    const int g = t3*128 + wave*16 + lrow;
    #pragma unroll
    for (int kk=0;kk<8;++kk)
      wf[t3][kk] = ld_w8s(Wih + g*NIN + kk*32 + lgrp*8, wscale[t3]);
    const float bv = wscale[t3] * (bih[g] + (t3<2 ? bhh[g] : 0.f));
    cinit[t3][0]=bv; cinit[t3][1]=bv; cinit[t3][2]=bv; cinit[t3][3]=bv;
  }

  const int row = tid>>5, f8 = tid&31;
  const float* xsrc = y_aux + (size_t)(b0+row)*(TSTEPS*NIN) + (size_t)(tch*TC)*NIN + f8*8;
  {
    float4 a = *(const float4*)xsrc;
    float4 b = *(const float4*)(xsrc+4);
    union{uint u[4]; bf16x8 v;} c;
    c.u[0]=pk2(a.x,a.y); c.u[1]=pk2(a.z,a.w); c.u[2]=pk2(b.x,b.y); c.u[3]=pk2(b.z,b.w);
    *(bf16x8*)&xsh[0][row][f8*8] = c.v;
  }
  // depth-2 prefetch: t=1 and t=2 (TC >= 3)
  float4 Aa = *(const float4*)(xsrc + 1*NIN), Ab = *(const float4*)(xsrc + 1*NIN + 4);
  float4 Ba = *(const float4*)(xsrc + 2*NIN), Bb = *(const float4*)(xsrc + 2*NIN + 4);
  __syncthreads();

  size_t sidx = ((size_t)dir*TSTEPS + (size_t)(tch*TC))*GIDX_N
              + (size_t)((btile*8 + wave)*64 + lane);

  for (int k=0;k<TC;k+=2){
    // ----- step k (reads xsh[0], writes Aa/Ab -> xsh[1]) -----
    {
      f32x4 a0=cinit[0], a1=cinit[1], a2=cinit[2];
      #pragma unroll
      for (int kk=0;kk<8;++kk){
        bf16x8 a = *(const bf16x8*)&xsh[0][lrow][kk*32 + lgrp*8];
        a0 = __builtin_amdgcn_mfma_f32_16x16x32_bf16(a, wf[0][kk], a0, 0,0,0);
        a1 = __builtin_amdgcn_mfma_f32_16x16x32_bf16(a, wf[1][kk], a1, 0,0,0);
        a2 = __builtin_amdgcn_mfma_f32_16x16x32_bf16(a, wf[2][kk], a2, 0,0,0);
      }
      uint4 o4; o4.x=pk2(a0[0],a0[1]); o4.y=pk2(a0[2],a0[3]);
                o4.z=pk2(a1[0],a1[1]); o4.w=pk2(a1[2],a1[3]);
      uint2 o2; o2.x=pk2(a2[0],a2[1]); o2.y=pk2(a2[2],a2[3]);
      xp4[sidx]=o4; xp2[sidx]=o2; sidx += GIDX_N;
      union{uint u[4]; bf16x8 v;} c;
      c.u[0]=pk2(Aa.x,Aa.y); c.u[1]=pk2(Aa.z,Aa.w); c.u[2]=pk2(Ab.x,Ab.y); c.u[3]=pk2(Ab.z,Ab.w);
      *(bf16x8*)&xsh[1][row][f8*8] = c.v;
      const int t3 = (k+3 <= TC-1) ? (k+3) : (TC-1);     // uniform, clamped
      Aa = *(const float4*)(xsrc + (size_t)t3*NIN);
      Ab = *(const float4*)(xsrc + (size_t)t3*NIN + 4);
      asm volatile("s_waitcnt lgkmcnt(0)\n\ts_barrier" ::: "memory");
    }
    // ----- step k+1 (reads xsh[1], writes Ba/Bb -> xsh[0]) -----
    {
      f32x4 a0=cinit[0], a1=cinit[1], a2=cinit[2];
      #pragma unroll
      for (int kk=0;kk<8;++kk){
        bf16x8 a = *(const bf16x8*)&xsh[1][lrow][kk*32 + lgrp*8];
        a0 = __builtin_amdgcn_mfma_f32_16x16x32_bf16(a, wf[0][kk], a0, 0,0,0);
        a1 = __builtin_amdgcn_mfma_f32_16x16x32_bf16(a, wf[1][kk], a1, 0,0,0);
        a2 = __builtin_amdgcn_mfma_f32_16x16x32_bf16(a, wf[2][kk], a2, 0,0,0);
      }
      uint4 o4; o4.x=pk2(a0[0],a0[1]); o4.y=pk2(a0[2],a0[3]);
                o4.z=pk2(a1[0],a1[1]); o4.w=pk2(a1[2],a1[3]);
      uint2 o2; o2.x=pk2(a2[0],a2[1]); o2.y=pk2(a2[2],a2[3]);
      xp4[sidx]=o4; xp2[sidx]=o2; sidx += GIDX_N;
      union{uint u[4]; bf16x8 v;} c;
      c.u[0]=pk2(Ba.x,Ba.y); c.u[1]=pk2(Ba.z,Ba.w); c.u[2]=pk2(Bb.x,Bb.y); c.u[3]=pk2(Bb.z,Bb.w);
      *(bf16x8*)&xsh[0][row][f8*8] = c.v;
      const int t4 = (k+4 <= TC-1) ? (k+4) : (TC-1);
      Ba = *(const float4*)(xsrc + (size_t)t4*NIN);
      Bb = *(const float4*)(xsrc + (size_t)t4*NIN + 4);
      asm volatile("s_waitcnt lgkmcnt(0)\n\ts_barrier" ::: "memory");
    }
  }
}

// ============================================================================
// Serial recurrence: 32 blocks (dir x btile), 8 waves; wave w owns gate tiles
// {w, 8+w, 16+w} = (r,z,n) for h columns [16w,16w+16). xp preacts are folded
// in as MFMA C-operand inits; n-path prescaled by 2*log2e.
// ============================================================================
__global__ __launch_bounds__(512) void gru_rec(
    const uint4* __restrict__ xp4, const uint2* __restrict__ xp2,
    const float* __restrict__ Whhf, const float* __restrict__ bhhf,
    const float* __restrict__ Whhb, const float* __restrict__ bhhb,
    float* __restrict__ out)
{
  const int blk=blockIdx.x, dir=blk>>4, btile=blk&15, b0=btile<<4;
  const int tid=threadIdx.x, wave=tid>>6, lane=tid&63, lrow=lane&15, lgrp=lane>>4;
  const float* Whh = dir? Whhb : Whhf;
  const float* bhh = dir? bhhb : bhhf;

  __shared__ __align__(16) ushort hbuf[2][16][136];

  bf16x8 whh[3][4];
  #pragma unroll
  for (int t3=0;t3<3;++t3){
    const int g = t3*128 + wave*16 + lrow;
    const float s = (t3<2)? LOG2E : 2.f*LOG2E;
    #pragma unroll
    for (int kk=0;kk<4;++kk)
      whh[t3][kk] = ld_w8s(Whh + g*HID + kk*32 + lgrp*8, s);
  }
  const int hcol = wave*16 + lrow;
  const float bh2s = 2.f*LOG2E * bhh[256 + hcol];
  f32x4 aninit; aninit[0]=bh2s; aninit[1]=bh2s; aninit[2]=bh2s; aninit[3]=bh2s;

  { ushort* hb=&hbuf[0][0][0]; for (int i=tid;i<16*136;i+=512) hb[i]=0; }

  const int tt0 = dir? (TSTEPS-1):0;
  const long long d4 = dir? -(long long)GIDX_N : (long long)GIDX_N;
  const size_t gbase = ((size_t)dir*TSTEPS + (size_t)tt0)*GIDX_N
                     + (size_t)((btile*8+wave)*64+lane);
  const uint4* q4p = xp4 + gbase;
  const uint2* q2p = xp2 + gbase;
  uint4 q40 = q4p[0], q41 = q4p[d4];
  uint2 q20 = q2p[0], q21 = q2p[d4];
  const uint4* f4 = q4p + 2*d4;
  const uint2* f2 = q2p + 2*d4;

  float* op = out + 8192 + (size_t)tt0*(BATCH*2*HID)
            + (size_t)(b0 + lgrp*4)*(2*HID) + dir*HID + hcol;
  const long long odel = dir? -(long long)(BATCH*2*HID) : (long long)(BATCH*2*HID);

  float hm[4]={0,0,0,0};
  __syncthreads();

  #pragma unroll 2
  for (int s=0;s<TSTEPS;++s){
    const int cur=s&1, nxt=cur^1;
    // depth-2 prefetch (wrap-safe inside xp4/xp2 allocations)
    uint4 q42 = *f4; f4 += d4;
    uint2 q22 = *f2; f2 += d4;

    // xp preacts -> MFMA C-operand inits
    f32x4 xrv; xrv[0]=bflo(q40.x); xrv[1]=bfhi(q40.x); xrv[2]=bflo(q40.y); xrv[3]=bfhi(q40.y);
    f32x4 xzv; xzv[0]=bflo(q40.z); xzv[1]=bfhi(q40.z); xzv[2]=bflo(q40.w); xzv[3]=bfhi(q40.w);
    float xnv[4] = {bflo(q20.x),bfhi(q20.x),bflo(q20.y),bfhi(q20.y)};

    bf16x8 ha[4];
    #pragma unroll
    for (int kk=0;kk<4;++kk)
      ha[kk] = *(const bf16x8*)&hbuf[cur][lrow][kk*32 + lgrp*8];

    f32x4 ar = __builtin_amdgcn_mfma_f32_16x16x32_bf16(ha[0], whh[0][0], xrv,    0,0,0);
    f32x4 az = __builtin_amdgcn_mfma_f32_16x16x32_bf16(ha[0], whh[1][0], xzv,    0,0,0);
    f32x4 an = __builtin_amdgcn_mfma_f32_16x16x32_bf16(ha[0], whh[2][0], aninit, 0,0,0);
    #pragma unroll
    for (int kk=1;kk<4;++kk){
      ar = __builtin_amdgcn_mfma_f32_16x16x32_bf16(ha[kk], whh[0][kk], ar, 0,0,0);
      az = __builtin_amdgcn_mfma_f32_16x16x32_bf16(ha[kk], whh[1][kk], az, 0,0,0);
      an = __builtin_amdgcn_mfma_f32_16x16x32_bf16(ha[kk], whh[2][kk], an, 0,0,0);
    }

    float hv[4];
    #pragma unroll
    for (int i=0;i<4;++i){
      // ar/az/an already hold the full log2e-scaled preacts
      const float r  = __builtin_amdgcn_rcpf(1.f + __builtin_amdgcn_exp2f(-ar[i]));
      const float z  = __builtin_amdgcn_rcpf(1.f + __builtin_amdgcn_exp2f(-az[i]));
      const float y2 = fmaf(r, an[i], xnv[i]);          // = 2*log2e*tanh-arg
      const float e  = __builtin_amdgcn_exp2f(fabsf(y2));
      const float t  = fmaf(-2.f, __builtin_amdgcn_rcpf(e+1.f), 1.f);
      const float n  = copysignf(t, y2);
      hv[i] = fmaf(z, hm[i]-n, n);
      hm[i] = hv[i];
    }
    const uint p01 = pk2(hv[0],hv[1]);
    const uint p23 = pk2(hv[2],hv[3]);
    hbuf[nxt][lgrp*4+0][hcol] = (ushort)p01;
    hbuf[nxt][lgrp*4+1][hcol] = (ushort)(p01>>16);
    hbuf[nxt][lgrp*4+2][hcol] = (ushort)p23;
    hbuf[nxt][lgrp*4+3][hcol] = (ushort)(p23>>16);
    op[0]   = hv[0];
    op[256] = hv[1];
    op[512] = hv[2];
    op[768] = hv[3];
    op += odel;
    q40=q41; q41=q42; q20=q21; q21=q22;
    asm volatile("s_waitcnt lgkmcnt(0)\n\ts_barrier" ::: "memory");
  }
}

// ============================================================================
// Fallback fused kernel (used only if ws_size is too small)
// ============================================================================
__global__ __launch_bounds__(512) void gru_fused(
    const float* __restrict__ y_aux,
    const float* __restrict__ W_ih_f, const float* __restrict__ W_hh_f,
    const float* __restrict__ b_ih_f, const float* __restrict__ b_hh_f,
    const float* __restrict__ W_ih_b, const float* __restrict__ W_hh_b,
    const float* __restrict__ b_ih_b, const float* __restrict__ b_hh_b,
    float* __restrict__ out)
{
  const int blk  = blockIdx.x;
  const int dir  = blk >> 4;
  const int b0   = (blk & 15) << 4;
  const int tid  = threadIdx.x;
  const int wave = tid >> 6;
  const int lane = tid & 63;
  const int lrow = lane & 15;
  const int lgrp = lane >> 4;

  const float* Wih = dir ? W_ih_b : W_ih_f;
  const float* Whh = dir ? W_hh_b : W_hh_f;
  const float* bih = dir ? b_ih_b : b_ih_f;
  const float* bhh = dir ? b_hh_b : b_hh_f;

  __shared__ __align__(16) ushort hbuf[2][16][136];
  __shared__ __align__(16) ushort xbuf[2][16][264];

  bf16x8 wih_f[3][8];
  bf16x8 whh_f[3][4];
  #pragma unroll
  for (int t3 = 0; t3 < 3; ++t3){
    const int g = t3*128 + wave*16 + lrow;
    #pragma unroll
    for (int kk = 0; kk < 8; ++kk) wih_f[t3][kk] = ld_w8(Wih + g*NIN + kk*32 + lgrp*8);
    #pragma unroll
    for (int kk = 0; kk < 4; ++kk) whh_f[t3][kk] = ld_w8(Whh + g*HID + kk*32 + lgrp*8);
  }
  float bihv[3], bhhv[3];
  #pragma unroll
  for (int t3 = 0; t3 < 3; ++t3){
    const int g = t3*128 + wave*16 + lrow;
    bihv[t3] = bih[g];
    bhhv[t3] = bhh[g];
  }

  for (int i = tid; i < 2*16*136; i += 512) ((ushort*)hbuf)[i] = 0;
  {
    const int row = tid >> 5, f8 = tid & 31;
    const int t0  = dir ? (TSTEPS-1) : 0;
    const float* p = y_aux + (size_t)(b0+row)*(TSTEPS*NIN) + (size_t)t0*NIN + f8*8;
    union{uint u[4]; bf16x8 v;} c;
    float4 a = *(const float4*)p; float4 b = *(const float4*)(p+4);
    c.u[0]=pk2(a.x,a.y); c.u[1]=pk2(a.z,a.w); c.u[2]=pk2(b.x,b.y); c.u[3]=pk2(b.z,b.w);
    *(bf16x8*)&xbuf[0][row][f8*8] = c.v;
  }
  __syncthreads();

  float hm[4] = {0.f, 0.f, 0.f, 0.f};
  const int hcol = wave*16 + lrow;
  float* outr = out + 8192;

  for (int s = 0; s < TSTEPS; ++s){
    const int tt  = dir ? (TSTEPS-1-s) : s;
    const int cur = s & 1, nxt = cur ^ 1;
    const int tn   = dir ? (tt-1) : (tt+1);
    const int prow = tid >> 5, pf8 = tid & 31;
    const bool more = (s < TSTEPS-1);
    float4 pa, pb;
    if (more){
      const float* p = y_aux + (size_t)(b0+prow)*(TSTEPS*NIN) + (size_t)tn*NIN + pf8*8;
      pa = *(const float4*)p;
      pb = *(const float4*)(p+4);
    }

    f32x4 a_rh = {0,0,0,0}, a_zh = {0,0,0,0}, a_nh = {0,0,0,0};
    f32x4 a_rx = {0,0,0,0}, a_zx = {0,0,0,0}, a_nx = {0,0,0,0};
    #pragma unroll
    for (int kk = 0; kk < 4; ++kk){
      bf16x8 a = *(const bf16x8*)&hbuf[cur][lrow][kk*32 + lgrp*8];
      a_rh = __builtin_amdgcn_mfma_f32_16x16x32_bf16(a, whh_f[0][kk], a_rh, 0,0,0);
      a_zh = __builtin_amdgcn_mfma_f32_16x16x32_bf16(a, whh_f[1][kk], a_zh, 0,0,0);
      a_nh = __builtin_amdgcn_mfma_f32_16x16x32_bf16(a, whh_f[2][kk], a_nh, 0,0,0);
    }
    #pragma unroll
    for (int kk = 0; kk < 8; ++kk){
      bf16x8 a = *(const bf16x8*)&xbuf[cur][lrow][kk*32 + lgrp*8];
      a_rx = __builtin_amdgcn_mfma_f32_16x16x32_bf16(a, wih_f[0][kk], a_rx, 0,0,0);
      a_zx = __builtin_amdgcn_mfma_f32_16x16x32_bf16(a, wih_f[1][kk], a_zx, 0,0,0);
      a_nx = __builtin_amdgcn_mfma_f32_16x16x32_bf16(a, wih_f[2][kk], a_nx, 0,0,0);
    }

    #pragma unroll
    for (int i = 0; i < 4; ++i){
      const float rp  = a_rh[i] + a_rx[i] + bihv[0] + bhhv[0];
      const float zp  = a_zh[i] + a_zx[i] + bihv[1] + bhhv[1];
      const float hnp = a_nh[i] + bhhv[2];
      const float xnp = a_nx[i] + bihv[2];
      const float r = sigmoid_fast(rp);
      const float z = sigmoid_fast(zp);
      const float n = tanh_fast(fmaf(r, hnp, xnp));
      const float hv = n + z*(hm[i] - n);
      hm[i] = hv;
      outr[(size_t)tt*(BATCH*2*HID) + (size_t)(b0 + lgrp*4 + i)*(2*HID)
           + dir*HID + hcol] = hv;
      hbuf[nxt][lgrp*4 + i][hcol] = f2bf(hv);
    }

    if (more){
      union{uint u[4]; bf16x8 v;} c;
      c.u[0]=pk2(pa.x,pa.y); c.u[1]=pk2(pa.z,pa.w); c.u[2]=pk2(pb.x,pb.y); c.u[3]=pk2(pb.z,pb.w);
      *(bf16x8*)&xbuf[nxt][prow][pf8*8] = c.v;
    }
    __syncthreads();
  }
}

// mu_0 / log_var_0 heads: temp = [zeros(B,L), hn0], so only W[:, L:] matters.
__global__ void heads(const float* __restrict__ out_rnn,
    const float* __restrict__ W_mu, const float* __restrict__ b_mu,
    const float* __restrict__ W_lv, const float* __restrict__ b_lv,
    float* __restrict__ out)
{
  const int oid   = blockIdx.x*256 + threadIdx.x;
  const int which = oid >> 12;
  const int r     = oid & 4095;
  const int b = r >> 4, j = r & 15;
  const float* W    = which ? W_lv : W_mu;
  const float* bias = which ? b_lv : b_mu;
  const float* h = out_rnn + b*256;
  const float* w = W + j*272 + 16;
  float acc = bias[j];
  for (int c = 0; c < 256; c += 4){
    acc += h[c]*w[c] + h[c+1]*w[c+1] + h[c+2]*w[c+2] + h[c+3]*w[c+3];
  }
  out[(which << 12) + r] = acc;
}

extern "C" void kernel_launch(void* const* d_in, const int* in_sizes, int n_in,
                              void* d_out, int out_size, void* d_ws, size_t ws_size,
                              hipStream_t stream)
{
  const float* y    = (const float*)d_in[0];
  const float* Wihf = (const float*)d_in[1];
  const float* Whhf = (const float*)d_in[2];
  const float* bihf = (const float*)d_in[3];
  const float* bhhf = (const float*)d_in[4];
  const float* Wihb = (const float*)d_in[5];
  const float* Whhb = (const float*)d_in[6];
  const float* bihb = (const float*)d_in[7];
  const float* bhhb = (const float*)d_in[8];
  const float* Wmu  = (const float*)d_in[9];
  const float* bmu  = (const float*)d_in[10];
  const float* Wlv  = (const float*)d_in[11];
  const float* blv  = (const float*)d_in[12];
  float* out = (float*)d_out;

  if (ws_size >= (size_t)XP_NEED){
    uint4* xp4 = (uint4*)d_ws;
    uint2* xp2 = (uint2*)((char*)d_ws + XP2_OFF_BYTES);
    xp_gemm<<<dim3(2*16*(TSTEPS/TC)), dim3(512), 0, stream>>>(
        y, Wihf, bihf, bhhf, Wihb, bihb, bhhb, xp4, xp2);
    gru_rec<<<dim3(32), dim3(512), 0, stream>>>(
        xp4, xp2, Whhf, bhhf, Whhb, bhhb, out);
  } else {
    gru_fused<<<dim3(32), dim3(512), 0, stream>>>(
        y, Wihf, Whhf, bihf, bhhf, Wihb, Whhb, bihb, bhhb, out);
  }
  heads<<<dim3(32), dim3(256), 0, stream>>>(out + 8192, Wmu, bmu, Wlv, blv, out);
}

// Round 6
// 948.437 us; speedup vs baseline: 1.3912x; 1.0530x over previous
//
#include <hip/hip_runtime.h>
#include <hip/hip_bf16.h>

typedef short bf16x8 __attribute__((ext_vector_type(8)));
typedef float f32x4  __attribute__((ext_vector_type(4)));

#define TSTEPS 1000
#define BATCH  256
#define NIN    256
#define HID    128
#define TC     50
#define LOG2E  1.44269504088896f

// SoA xp: xp4 = uint4 region {r01,r23,z01,z23}, xp2 = uint2 region {n01,n23}.
// index = ((dir*TSTEPS + t)*8192 + gidx), gidx = (btile*8+wave)*64+lane.
// r,z prescaled by log2e (biases bih+bhh folded); n prescaled by 2*log2e
// (bih folded; bhh_n folded into gru_rec's an C-init).
#define GIDX_N 8192
#define XP4_ELEMS (2ull*TSTEPS*GIDX_N)
#define XP2_OFF_BYTES (XP4_ELEMS*16ull)           // 262,144,000
#define XP_NEED (XP4_ELEMS*16ull + 2ull*TSTEPS*GIDX_N*8ull)   // 393,216,000

__device__ __forceinline__ ushort f2bf(float f){
  union { float f; unsigned u; } v; v.f = f;
  unsigned r = v.u + 0x7fffu + ((v.u >> 16) & 1u);
  return (ushort)(r >> 16);
}
__device__ __forceinline__ uint pk2(float lo, float hi){
  __hip_bfloat162 h = __float22bfloat162_rn(make_float2(lo, hi));
  union { __hip_bfloat162 h; uint u; } c; c.h = h; return c.u;
}
__device__ __forceinline__ float bflo(uint w){ union{uint u;float f;}c; c.u = w<<16; return c.f; }
__device__ __forceinline__ float bfhi(uint w){ union{uint u;float f;}c; c.u = w & 0xffff0000u; return c.f; }

__device__ __forceinline__ float sigmoid_fast(float x){
  return __builtin_amdgcn_rcpf(1.f + __expf(-x));
}
__device__ __forceinline__ float tanh_fast(float a){
  const float e = __expf(2.f*fabsf(a));
  const float t = fmaf(-2.f, __builtin_amdgcn_rcpf(e + 1.f), 1.f);
  return copysignf(t, a);
}
__device__ __forceinline__ bf16x8 ld_w8(const float* p){
  union { uint u[4]; bf16x8 v; } c;
  c.u[0]=pk2(p[0],p[1]); c.u[1]=pk2(p[2],p[3]);
  c.u[2]=pk2(p[4],p[5]); c.u[3]=pk2(p[6],p[7]);
  return c.v;
}
__device__ __forceinline__ bf16x8 ld_w8s(const float* p, float s){
  union { uint u[4]; bf16x8 v; } c;
  c.u[0]=pk2(p[0]*s,p[1]*s); c.u[1]=pk2(p[2]*s,p[3]*s);
  c.u[2]=pk2(p[4]*s,p[5]*s); c.u[3]=pk2(p[6]*s,p[7]*s);
  return c.v;
}

// ============================================================================
// Input-projection GEMM. Weights prescaled (r,z: log2e; n: 2*log2e); biases
// folded via loop-invariant MFMA C-operand init. Depth-2 register prefetch.
// ============================================================================
__global__ __launch_bounds__(512) void xp_gemm(
    const float* __restrict__ y_aux,
    const float* __restrict__ Wf, const float* __restrict__ bihf, const float* __restrict__ bhhf,
    const float* __restrict__ Wb, const float* __restrict__ bihb, const float* __restrict__ bhhb,
    uint4* __restrict__ xp4, uint2* __restrict__ xp2)
{
  const int nch = TSTEPS/TC;
  const int blk = blockIdx.x;
  const int dir = blk / (16*nch);
  const int rem = blk % (16*nch);
  const int btile = rem / nch;
  const int tch = rem % nch;
  const int b0 = btile*16;
  const int tid=threadIdx.x, wave=tid>>6, lane=tid&63, lrow=lane&15, lgrp=lane>>4;
  const float* Wih = dir? Wb : Wf;
  const float* bih = dir? bihb : bihf;
  const float* bhh = dir? bhhb : bhhf;

  __shared__ __align__(16) ushort xsh[2][16][264];

  const float wscale[3] = {LOG2E, LOG2E, 2.f*LOG2E};
  bf16x8 wf[3][8];
  f32x4 cinit[3];
  #pragma unroll
  for (int t3=0;t3<3;++t3){
    const int g = t3*128 + wave*16 + lrow;
    #pragma unroll
    for (int kk=0;kk<8;++kk)
      wf[t3][kk] = ld_w8s(Wih + g*NIN + kk*32 + lgrp*8, wscale[t3]);
    const float bv = wscale[t3] * (bih[g] + (t3<2 ? bhh[g] : 0.f));
    cinit[t3][0]=bv; cinit[t3][1]=bv; cinit[t3][2]=bv; cinit[t3][3]=bv;
  }

  const int row = tid>>5, f8 = tid&31;
  const float* xsrc = y_aux + (size_t)(b0+row)*(TSTEPS*NIN) + (size_t)(tch*TC)*NIN + f8*8;
  {
    float4 a = *(const float4*)xsrc;
    float4 b = *(const float4*)(xsrc+4);
    union{uint u[4]; bf16x8 v;} c;
    c.u[0]=pk2(a.x,a.y); c.u[1]=pk2(a.z,a.w); c.u[2]=pk2(b.x,b.y); c.u[3]=pk2(b.z,b.w);
    *(bf16x8*)&xsh[0][row][f8*8] = c.v;
  }
  // depth-2 prefetch: t=1 and t=2 (TC >= 3)
  float4 Aa = *(const float4*)(xsrc + 1*NIN), Ab = *(const float4*)(xsrc + 1*NIN + 4);
  float4 Ba = *(const float4*)(xsrc + 2*NIN), Bb = *(const float4*)(xsrc + 2*NIN + 4);
  __syncthreads();

  size_t sidx = ((size_t)dir*TSTEPS + (size_t)(tch*TC))*GIDX_N
              + (size_t)((btile*8 + wave)*64 + lane);

  for (int k=0;k<TC;k+=2){
    // ----- step k (reads xsh[0], writes Aa/Ab -> xsh[1]) -----
    {
      f32x4 a0=cinit[0], a1=cinit[1], a2=cinit[2];
      #pragma unroll
      for (int kk=0;kk<8;++kk){
        bf16x8 a = *(const bf16x8*)&xsh[0][lrow][kk*32 + lgrp*8];
        a0 = __builtin_amdgcn_mfma_f32_16x16x32_bf16(a, wf[0][kk], a0, 0,0,0);
        a1 = __builtin_amdgcn_mfma_f32_16x16x32_bf16(a, wf[1][kk], a1, 0,0,0);
        a2 = __builtin_amdgcn_mfma_f32_16x16x32_bf16(a, wf[2][kk], a2, 0,0,0);
      }
      uint4 o4; o4.x=pk2(a0[0],a0[1]); o4.y=pk2(a0[2],a0[3]);
                o4.z=pk2(a1[0],a1[1]); o4.w=pk2(a1[2],a1[3]);
      uint2 o2; o2.x=pk2(a2[0],a2[1]); o2.y=pk2(a2[2],a2[3]);
      xp4[sidx]=o4; xp2[sidx]=o2; sidx += GIDX_N;
      union{uint u[4]; bf16x8 v;} c;
      c.u[0]=pk2(Aa.x,Aa.y); c.u[1]=pk2(Aa.z,Aa.w); c.u[2]=pk2(Ab.x,Ab.y); c.u[3]=pk2(Ab.z,Ab.w);
      *(bf16x8*)&xsh[1][row][f8*8] = c.v;
      const int t3 = (k+3 <= TC-1) ? (k+3) : (TC-1);     // uniform, clamped
      Aa = *(const float4*)(xsrc + (size_t)t3*NIN);
      Ab = *(const float4*)(xsrc + (size_t)t3*NIN + 4);
      asm volatile("s_waitcnt lgkmcnt(0)\n\ts_barrier" ::: "memory");
    }
    // ----- step k+1 (reads xsh[1], writes Ba/Bb -> xsh[0]) -----
    {
      f32x4 a0=cinit[0], a1=cinit[1], a2=cinit[2];
      #pragma unroll
      for (int kk=0;kk<8;++kk){
        bf16x8 a = *(const bf16x8*)&xsh[1][lrow][kk*32 + lgrp*8];
        a0 = __builtin_amdgcn_mfma_f32_16x16x32_bf16(a, wf[0][kk], a0, 0,0,0);
        a1 = __builtin_amdgcn_mfma_f32_16x16x32_bf16(a, wf[1][kk], a1, 0,0,0);
        a2 = __builtin_amdgcn_mfma_f32_16x16x32_bf16(a, wf[2][kk], a2, 0,0,0);
      }
      uint4 o4; o4.x=pk2(a0[0],a0[1]); o4.y=pk2(a0[2],a0[3]);
                o4.z=pk2(a1[0],a1[1]); o4.w=pk2(a1[2],a1[3]);
      uint2 o2; o2.x=pk2(a2[0],a2[1]); o2.y=pk2(a2[2],a2[3]);
      xp4[sidx]=o4; xp2[sidx]=o2; sidx += GIDX_N;
      union{uint u[4]; bf16x8 v;} c;
      c.u[0]=pk2(Ba.x,Ba.y); c.u[1]=pk2(Ba.z,Ba.w); c.u[2]=pk2(Bb.x,Bb.y); c.u[3]=pk2(Bb.z,Bb.w);
      *(bf16x8*)&xsh[0][row][f8*8] = c.v;
      const int t4 = (k+4 <= TC-1) ? (k+4) : (TC-1);
      Ba = *(const float4*)(xsrc + (size_t)t4*NIN);
      Bb = *(const float4*)(xsrc + (size_t)t4*NIN + 4);
      asm volatile("s_waitcnt lgkmcnt(0)\n\ts_barrier" ::: "memory");
    }
  }
}

// ============================================================================
// Serial recurrence: 32 blocks (dir x btile), 8 waves; wave w owns gate tiles
// {w, 8+w, 16+w} = (r,z,n) for h columns [16w,16w+16).
// R3 dataflow: zero/bias (loop-invariant) MFMA C-init, xp added POST-MFMA
// (keeps per-step xp data off the MFMA input path). Hand-unrolled 2x body
// with named qA/qB prefetch register sets (depth-2, no rotation movs).
// ============================================================================
__global__ __launch_bounds__(512) void gru_rec(
    const uint4* __restrict__ xp4, const uint2* __restrict__ xp2,
    const float* __restrict__ Whhf, const float* __restrict__ bhhf,
    const float* __restrict__ Whhb, const float* __restrict__ bhhb,
    float* __restrict__ out)
{
  const int blk=blockIdx.x, dir=blk>>4, btile=blk&15, b0=btile<<4;
  const int tid=threadIdx.x, wave=tid>>6, lane=tid&63, lrow=lane&15, lgrp=lane>>4;
  const float* Whh = dir? Whhb : Whhf;
  const float* bhh = dir? bhhb : bhhf;

  __shared__ __align__(16) ushort hbuf[2][16][136];

  bf16x8 whh[3][4];
  #pragma unroll
  for (int t3=0;t3<3;++t3){
    const int g = t3*128 + wave*16 + lrow;
    const float s = (t3<2)? LOG2E : 2.f*LOG2E;
    #pragma unroll
    for (int kk=0;kk<4;++kk)
      whh[t3][kk] = ld_w8s(Whh + g*HID + kk*32 + lgrp*8, s);
  }
  const int hcol = wave*16 + lrow;
  const float bh2s = 2.f*LOG2E * bhh[256 + hcol];
  f32x4 aninit; aninit[0]=bh2s; aninit[1]=bh2s; aninit[2]=bh2s; aninit[3]=bh2s;
  const f32x4 zero4 = {0.f,0.f,0.f,0.f};

  { ushort* hb=&hbuf[0][0][0]; for (int i=tid;i<16*136;i+=512) hb[i]=0; }

  const int tt0 = dir? (TSTEPS-1):0;
  const long long d4 = dir? -(long long)GIDX_N : (long long)GIDX_N;
  const size_t gbase = ((size_t)dir*TSTEPS + (size_t)tt0)*GIDX_N
                     + (size_t)((btile*8+wave)*64+lane);
  const uint4* q4p = xp4 + gbase;
  const uint2* q2p = xp2 + gbase;
  uint4 qA4 = q4p[0], qB4 = q4p[d4];
  uint2 qA2 = q2p[0], qB2 = q2p[d4];
  const uint4* f4 = q4p + 2*d4;
  const uint2* f2 = q2p + 2*d4;

  float* op = out + 8192 + (size_t)tt0*(BATCH*2*HID)
            + (size_t)(b0 + lgrp*4)*(2*HID) + dir*HID + hcol;
  const long long odel = dir? -(long long)(BATCH*2*HID) : (long long)(BATCH*2*HID);

  float hm[4]={0,0,0,0};
  __syncthreads();

  // one GRU step: reads hbuf[CUR], writes hbuf[NXT]; consumes Q4/Q2 and
  // reloads them for step s+2 at the bottom (no register rotation).
  #define GRU_STEP(CUR, NXT, Q4, Q2)                                          \
  {                                                                           \
    bf16x8 ha[4];                                                             \
    _Pragma("unroll")                                                         \
    for (int kk=0;kk<4;++kk)                                                  \
      ha[kk] = *(const bf16x8*)&hbuf[CUR][lrow][kk*32 + lgrp*8];              \
    f32x4 ar = __builtin_amdgcn_mfma_f32_16x16x32_bf16(ha[0], whh[0][0], zero4, 0,0,0); \
    f32x4 az = __builtin_amdgcn_mfma_f32_16x16x32_bf16(ha[0], whh[1][0], zero4, 0,0,0); \
    f32x4 an = __builtin_amdgcn_mfma_f32_16x16x32_bf16(ha[0], whh[2][0], aninit, 0,0,0); \
    _Pragma("unroll")                                                         \
    for (int kk=1;kk<4;++kk){                                                 \
      ar = __builtin_amdgcn_mfma_f32_16x16x32_bf16(ha[kk], whh[0][kk], ar, 0,0,0); \
      az = __builtin_amdgcn_mfma_f32_16x16x32_bf16(ha[kk], whh[1][kk], az, 0,0,0); \
      an = __builtin_amdgcn_mfma_f32_16x16x32_bf16(ha[kk], whh[2][kk], an, 0,0,0); \
    }                                                                         \
    const float xr[4]={bflo(Q4.x),bfhi(Q4.x),bflo(Q4.y),bfhi(Q4.y)};          \
    const float xz[4]={bflo(Q4.z),bfhi(Q4.z),bflo(Q4.w),bfhi(Q4.w)};          \
    const float xn[4]={bflo(Q2.x),bfhi(Q2.x),bflo(Q2.y),bfhi(Q2.y)};          \
    float hv[4];                                                              \
    _Pragma("unroll")                                                         \
    for (int i=0;i<4;++i){                                                    \
      const float r  = __builtin_amdgcn_rcpf(1.f + __builtin_amdgcn_exp2f(-(ar[i]+xr[i]))); \
      const float z  = __builtin_amdgcn_rcpf(1.f + __builtin_amdgcn_exp2f(-(az[i]+xz[i]))); \
      const float y2 = fmaf(r, an[i], xn[i]);                                 \
      const float e  = __builtin_amdgcn_exp2f(fabsf(y2));                     \
      const float t  = fmaf(-2.f, __builtin_amdgcn_rcpf(e+1.f), 1.f);         \
      const float n  = copysignf(t, y2);                                      \
      hv[i] = fmaf(z, hm[i]-n, n);                                            \
      hm[i] = hv[i];                                                          \
    }                                                                         \
    const uint p01 = pk2(hv[0],hv[1]);                                        \
    const uint p23 = pk2(hv[2],hv[3]);                                        \
    hbuf[NXT][lgrp*4+0][hcol] = (ushort)p01;                                  \
    hbuf[NXT][lgrp*4+1][hcol] = (ushort)(p01>>16);                            \
    hbuf[NXT][lgrp*4+2][hcol] = (ushort)p23;                                  \
    hbuf[NXT][lgrp*4+3][hcol] = (ushort)(p23>>16);                            \
    Q4 = *f4; f4 += d4;                                                       \
    Q2 = *f2; f2 += d4;                                                       \
    op[0]   = hv[0];                                                          \
    op[256] = hv[1];                                                          \
    op[512] = hv[2];                                                          \
    op[768] = hv[3];                                                          \
    op += odel;                                                               \
    asm volatile("s_waitcnt lgkmcnt(0)\n\ts_barrier" ::: "memory");           \
  }

  for (int s=0;s<TSTEPS;s+=2){
    GRU_STEP(0, 1, qA4, qA2)
    GRU_STEP(1, 0, qB4, qB2)
  }
  #undef GRU_STEP
}

// ============================================================================
// Fallback fused kernel (used only if ws_size is too small)
// ============================================================================
__global__ __launch_bounds__(512) void gru_fused(
    const float* __restrict__ y_aux,
    const float* __restrict__ W_ih_f, const float* __restrict__ W_hh_f,
    const float* __restrict__ b_ih_f, const float* __restrict__ b_hh_f,
    const float* __restrict__ W_ih_b, const float* __restrict__ W_hh_b,
    const float* __restrict__ b_ih_b, const float* __restrict__ b_hh_b,
    float* __restrict__ out)
{
  const int blk  = blockIdx.x;
  const int dir  = blk >> 4;
  const int b0   = (blk & 15) << 4;
  const int tid  = threadIdx.x;
  const int wave = tid >> 6;
  const int lane = tid & 63;
  const int lrow = lane & 15;
  const int lgrp = lane >> 4;

  const float* Wih = dir ? W_ih_b : W_ih_f;
  const float* Whh = dir ? W_hh_b : W_hh_f;
  const float* bih = dir ? b_ih_b : b_ih_f;
  const float* bhh = dir ? b_hh_b : b_hh_f;

  __shared__ __align__(16) ushort hbuf[2][16][136];
  __shared__ __align__(16) ushort xbuf[2][16][264];

  bf16x8 wih_f[3][8];
  bf16x8 whh_f[3][4];
  #pragma unroll
  for (int t3 = 0; t3 < 3; ++t3){
    const int g = t3*128 + wave*16 + lrow;
    #pragma unroll
    for (int kk = 0; kk < 8; ++kk) wih_f[t3][kk] = ld_w8(Wih + g*NIN + kk*32 + lgrp*8);
    #pragma unroll
    for (int kk = 0; kk < 4; ++kk) whh_f[t3][kk] = ld_w8(Whh + g*HID + kk*32 + lgrp*8);
  }
  float bihv[3], bhhv[3];
  #pragma unroll
  for (int t3 = 0; t3 < 3; ++t3){
    const int g = t3*128 + wave*16 + lrow;
    bihv[t3] = bih[g];
    bhhv[t3] = bhh[g];
  }

  for (int i = tid; i < 2*16*136; i += 512) ((ushort*)hbuf)[i] = 0;
  {
    const int row = tid >> 5, f8 = tid & 31;
    const int t0  = dir ? (TSTEPS-1) : 0;
    const float* p = y_aux + (size_t)(b0+row)*(TSTEPS*NIN) + (size_t)t0*NIN + f8*8;
    union{uint u[4]; bf16x8 v;} c;
    float4 a = *(const float4*)p; float4 b = *(const float4*)(p+4);
    c.u[0]=pk2(a.x,a.y); c.u[1]=pk2(a.z,a.w); c.u[2]=pk2(b.x,b.y); c.u[3]=pk2(b.z,b.w);
    *(bf16x8*)&xbuf[0][row][f8*8] = c.v;
  }
  __syncthreads();

  float hm[4] = {0.f, 0.f, 0.f, 0.f};
  const int hcol = wave*16 + lrow;
  float* outr = out + 8192;

  for (int s = 0; s < TSTEPS; ++s){
    const int tt  = dir ? (TSTEPS-1-s) : s;
    const int cur = s & 1, nxt = cur ^ 1;
    const int tn   = dir ? (tt-1) : (tt+1);
    const int prow = tid >> 5, pf8 = tid & 31;
    const bool more = (s < TSTEPS-1);
    float4 pa, pb;
    if (more){
      const float* p = y_aux + (size_t)(b0+prow)*(TSTEPS*NIN) + (size_t)tn*NIN + pf8*8;
      pa = *(const float4*)p;
      pb = *(const float4*)(p+4);
    }

    f32x4 a_rh = {0,0,0,0}, a_zh = {0,0,0,0}, a_nh = {0,0,0,0};
    f32x4 a_rx = {0,0,0,0}, a_zx = {0,0,0,0}, a_nx = {0,0,0,0};
    #pragma unroll
    for (int kk = 0; kk < 4; ++kk){
      bf16x8 a = *(const bf16x8*)&hbuf[cur][lrow][kk*32 + lgrp*8];
      a_rh = __builtin_amdgcn_mfma_f32_16x16x32_bf16(a, whh_f[0][kk], a_rh, 0,0,0);
      a_zh = __builtin_amdgcn_mfma_f32_16x16x32_bf16(a, whh_f[1][kk], a_zh, 0,0,0);
      a_nh = __builtin_amdgcn_mfma_f32_16x16x32_bf16(a, whh_f[2][kk], a_nh, 0,0,0);
    }
    #pragma unroll
    for (int kk = 0; kk < 8; ++kk){
      bf16x8 a = *(const bf16x8*)&xbuf[cur][lrow][kk*32 + lgrp*8];
      a_rx = __builtin_amdgcn_mfma_f32_16x16x32_bf16(a, wih_f[0][kk], a_rx, 0,0,0);
      a_zx = __builtin_amdgcn_mfma_f32_16x16x32_bf16(a, wih_f[1][kk], a_zx, 0,0,0);
      a_nx = __builtin_amdgcn_mfma_f32_16x16x32_bf16(a, wih_f[2][kk], a_nx, 0,0,0);
    }

    #pragma unroll
    for (int i = 0; i < 4; ++i){
      const float rp  = a_rh[i] + a_rx[i] + bihv[0] + bhhv[0];
      const float zp  = a_zh[i] + a_zx[i] + bihv[1] + bhhv[1];
      const float hnp = a_nh[i] + bhhv[2];
      const float xnp = a_nx[i] + bihv[2];
      const float r = sigmoid_fast(rp);
      const float z = sigmoid_fast(zp);
      const float n = tanh_fast(fmaf(r, hnp, xnp));
      const float hv = n + z*(hm[i] - n);
      hm[i] = hv;
      outr[(size_t)tt*(BATCH*2*HID) + (size_t)(b0 + lgrp*4 + i)*(2*HID)
           + dir*HID + hcol] = hv;
      hbuf[nxt][lgrp*4 + i][hcol] = f2bf(hv);
    }

    if (more){
      union{uint u[4]; bf16x8 v;} c;
      c.u[0]=pk2(pa.x,pa.y); c.u[1]=pk2(pa.z,pa.w); c.u[2]=pk2(pb.x,pb.y); c.u[3]=pk2(pb.z,pb.w);
      *(bf16x8*)&xbuf[nxt][prow][pf8*8] = c.v;
    }
    __syncthreads();
  }
}

// mu_0 / log_var_0 heads: temp = [zeros(B,L), hn0], so only W[:, L:] matters.
__global__ void heads(const float* __restrict__ out_rnn,
    const float* __restrict__ W_mu, const float* __restrict__ b_mu,
    const float* __restrict__ W_lv, const float* __restrict__ b_lv,
    float* __restrict__ out)
{
  const int oid   = blockIdx.x*256 + threadIdx.x;
  const int which = oid >> 12;
  const int r     = oid & 4095;
  const int b = r >> 4, j = r & 15;
  const float* W    = which ? W_lv : W_mu;
  const float* bias = which ? b_lv : b_mu;
  const float* h = out_rnn + b*256;
  const float* w = W + j*272 + 16;
  float acc = bias[j];
  for (int c = 0; c < 256; c += 4){
    acc += h[c]*w[c] + h[c+1]*w[c+1] + h[c+2]*w[c+2] + h[c+3]*w[c+3];
  }
  out[(which << 12) + r] = acc;
}

extern "C" void kernel_launch(void* const* d_in, const int* in_sizes, int n_in,
                              void* d_out, int out_size, void* d_ws, size_t ws_size,
                              hipStream_t stream)
{
  const float* y    = (const float*)d_in[0];
  const float* Wihf = (const float*)d_in[1];
  const float* Whhf = (const float*)d_in[2];
  const float* bihf = (const float*)d_in[3];
  const float* bhhf = (const float*)d_in[4];
  const float* Wihb = (const float*)d_in[5];
  const float* Whhb = (const float*)d_in[6];
  const float* bihb = (const float*)d_in[7];
  const float* bhhb = (const float*)d_in[8];
  const float* Wmu  = (const float*)d_in[9];
  const float* bmu  = (const float*)d_in[10];
  const float* Wlv  = (const float*)d_in[11];
  const float* blv  = (const float*)d_in[12];
  float* out = (float*)d_out;

  if (ws_size >= (size_t)XP_NEED){
    uint4* xp4 = (uint4*)d_ws;
    uint2* xp2 = (uint2*)((char*)d_ws + XP2_OFF_BYTES);
    xp_gemm<<<dim3(2*16*(TSTEPS/TC)), dim3(512), 0, stream>>>(
        y, Wihf, bihf, bhhf, Wihb, bihb, bhhb, xp4, xp2);
    gru_rec<<<dim3(32), dim3(512), 0, stream>>>(
        xp4, xp2, Whhf, bhhf, Whhb, bhhb, out);
  } else {
    gru_fused<<<dim3(32), dim3(512), 0, stream>>>(
        y, Wihf, Whhf, bihf, bhhf, Wihb, Whhb, bihb, bhhb, out);
  }
  heads<<<dim3(32), dim3(256), 0, stream>>>(out + 8192, Wmu, bmu, Wlv, blv, out);
}